// Round 2
// baseline (374.721 us; speedup 1.0000x reference)
//
#include <hip/hip_runtime.h>

// Problem constants (from reference setup_inputs): B=4, S=8192, D=1024, fp32.
constexpr int B  = 4;
constexpr int S  = 8192;
constexpr int D  = 1024;
constexpr int C  = 512;        // chunks along S (was 128): 2048 blocks = 8 blocks/CU
constexpr int L  = S / C;      // 16 steps per chunk
constexpr int D4 = D / 4;      // 256 float4 per (b, s) row — exactly one 256-thread block

// Native clang vector type — __builtin_nontemporal_store rejects HIP's float4 class.
typedef float nt_float4 __attribute__((ext_vector_type(4)));

// ---------------- Phase 1: per-chunk aggregates ----------------
// Block (c, b): scan chunk c of batch b. Thread t owns float4 of 4 channels.
// X = chunk-combine result with h_in = 0, A = prod(alpha) over chunk.
// __launch_bounds__(256, 8): 8 waves/SIMD -> VGPR <= 64, 32 waves/CU, so the
// unroll-4 load pairs (8 float4 in flight) actually stay in registers.
__global__ __launch_bounds__(256, 8) void phase1(const float4* __restrict__ x,
                                                 const float4* __restrict__ a,
                                                 float4* __restrict__ Xagg,
                                                 float4* __restrict__ Aagg) {
    const int t = threadIdx.x;         // 0..255
    const int c = blockIdx.x;          // chunk
    const int b = blockIdx.y;          // batch
    const long base = ((long)(b * S + c * L)) * D4 + t;

    float4 X = {0.f, 0.f, 0.f, 0.f};
    float4 A = {1.f, 1.f, 1.f, 1.f};
    #pragma unroll 4
    for (int s = 0; s < L; ++s) {
        float4 xv = x[base + (long)s * D4];
        float4 av = a[base + (long)s * D4];
        X.x = fmaf(av.x, X.x, xv.x);
        X.y = fmaf(av.y, X.y, xv.y);
        X.z = fmaf(av.z, X.z, xv.z);
        X.w = fmaf(av.w, X.w, xv.w);
        A.x *= av.x; A.y *= av.y; A.z *= av.z; A.w *= av.w;
    }
    const long o = ((long)(b * C + c)) * D4 + t;
    Xagg[o] = X;
    Aagg[o] = A;
}

// ---------------- Phase 2: scan across chunk aggregates ----------------
// One thread per scalar channel (b, d). Overwrites Xagg with the EXCLUSIVE
// prefix (h entering chunk c). Hand-pipelined 4-wide: all loads of a group
// are issued before any store, so they overlap. 64-thread blocks spread the
// 4096 threads over 64 CUs instead of 16.
__global__ __launch_bounds__(64) void phase2(float* __restrict__ Xagg,
                                             const float* __restrict__ Aagg) {
    const int g = blockIdx.x * 64 + threadIdx.x;  // 0..B*D-1
    const int b = g >> 10;                        // / D
    const int d = g & (D - 1);                    // % D
    float*       Xp = Xagg + (long)b * C * D + d;
    const float* Ap = Aagg + (long)b * C * D + d;
    float carry = 0.f;
    for (int c = 0; c < C; c += 4) {
        const long o0 = (long)c * D, o1 = o0 + D, o2 = o1 + D, o3 = o2 + D;
        const float X0 = Xp[o0], X1 = Xp[o1], X2 = Xp[o2], X3 = Xp[o3];
        const float A0 = Ap[o0], A1 = Ap[o1], A2 = Ap[o2], A3 = Ap[o3];
        Xp[o0] = carry; carry = fmaf(A0, carry, X0);
        Xp[o1] = carry; carry = fmaf(A1, carry, X1);
        Xp[o2] = carry; carry = fmaf(A2, carry, X2);
        Xp[o3] = carry; carry = fmaf(A3, carry, X3);
    }
}

// ---------------- Phase 3: re-scan chunks with incoming prefix ----------------
// Nontemporal stores: out is never re-read; don't let it evict x/a from L3.
__global__ __launch_bounds__(256, 8) void phase3(const float4* __restrict__ x,
                                                 const float4* __restrict__ a,
                                                 const float4* __restrict__ prefix,
                                                 float4* __restrict__ out) {
    const int t = threadIdx.x;
    const int c = blockIdx.x;
    const int b = blockIdx.y;

    float4 h = prefix[((long)(b * C + c)) * D4 + t];
    const long base = ((long)(b * S + c * L)) * D4 + t;
    nt_float4* ntout = (nt_float4*)out;
    #pragma unroll 4
    for (int s = 0; s < L; ++s) {
        float4 xv = x[base + (long)s * D4];
        float4 av = a[base + (long)s * D4];
        h.x = fmaf(av.x, h.x, xv.x);
        h.y = fmaf(av.y, h.y, xv.y);
        h.z = fmaf(av.z, h.z, xv.z);
        h.w = fmaf(av.w, h.w, xv.w);
        nt_float4 hv = {h.x, h.y, h.z, h.w};
        __builtin_nontemporal_store(hv, &ntout[base + (long)s * D4]);
    }
}

extern "C" void kernel_launch(void* const* d_in, const int* in_sizes, int n_in,
                              void* d_out, int out_size, void* d_ws, size_t ws_size,
                              hipStream_t stream) {
    const float4* x = (const float4*)d_in[0];
    const float4* a = (const float4*)d_in[1];
    float4* out = (float4*)d_out;

    // Workspace layout: Xagg (B*C*D floats) | Aagg (B*C*D floats) = 8 MiB each.
    float* Xagg = (float*)d_ws;
    float* Aagg = Xagg + (size_t)B * C * D;

    dim3 grid1(C, B);
    phase1<<<grid1, 256, 0, stream>>>(x, a, (float4*)Xagg, (float4*)Aagg);

    phase2<<<(B * D) / 64, 64, 0, stream>>>(Xagg, Aagg);

    phase3<<<grid1, 256, 0, stream>>>(x, a, (const float4*)Xagg, out);
}